// Round 1
// 1502.796 us; speedup vs baseline: 1.3437x; 1.3437x over previous
//
#include <hip/hip_runtime.h>
#include <cstddef>

#define B_    8
#define H_    32
#define W_    32
#define L_    6
#define R_    384
#define NH_   6
#define DH_   64
#define M_    1365
#define MPAD_ 1408
#define NE_   2304
#define HID_  9216
#define NROW_ 49152   // B*H*W*L
#define BMR_  10920   // B*M

typedef __bf16 bf16x8 __attribute__((ext_vector_type(8)));
typedef float  f32x4  __attribute__((ext_vector_type(4)));
typedef unsigned short us;

__device__ __forceinline__ unsigned short f2b(float f){
  unsigned u = __float_as_uint(f);
  u = (u + 0x7FFFu + ((u >> 16) & 1u)) >> 16;
  return (unsigned short)u;
}

__device__ __forceinline__ void gload16(const unsigned short* g, unsigned short* l){
  __builtin_amdgcn_global_load_lds(
      (const __attribute__((address_space(1))) unsigned int*)g,
      (__attribute__((address_space(3))) unsigned int*)l,
      16, 0, 0);
}

__device__ __forceinline__ float wsum(float s){
  #pragma unroll
  for (int o = 32; o > 0; o >>= 1) s += __shfl_xor(s, o, 64);
  return s;
}

__device__ __forceinline__ float rmax16(float v){
  v = fmaxf(v, __shfl_xor(v, 1, 64));
  v = fmaxf(v, __shfl_xor(v, 2, 64));
  v = fmaxf(v, __shfl_xor(v, 4, 64));
  v = fmaxf(v, __shfl_xor(v, 8, 64));
  return v;
}
__device__ __forceinline__ float rsum16(float v){
  v += __shfl_xor(v, 1, 64);
  v += __shfl_xor(v, 2, 64);
  v += __shfl_xor(v, 4, 64);
  v += __shfl_xor(v, 8, 64);
  return v;
}

__device__ __forceinline__ float gelu_tanh(float x){
  float t = tanhf(0.7978845608028654f * (x + 0.044715f * x * x * x));
  return 0.5f * x * (1.0f + t);
}

// ---------------- LN1 + scaled atomic scatter into uniq (B,M,R) ----------------
__global__ __launch_bounds__(256) void k_ln1_scatter(
    const float* __restrict__ x, const float* __restrict__ lw,
    const float* __restrict__ lb, float* __restrict__ uniq){
  int row  = blockIdx.x * 4 + (threadIdx.x >> 6);
  int lane = threadIdx.x & 63;
  int l  = row % 6;
  int hw = (row / 6) & 1023;
  int b  = row / 6144;
  int h = hw >> 5, w = hw & 31;
  const float* xr = x + (size_t)row * R_;
  float v[6]; float s = 0.f;
  #pragma unroll
  for (int i = 0; i < 6; i++){ v[i] = xr[lane + i*64]; s += v[i]; }
  s = wsum(s);
  float mu = s * (1.f/384.f);
  float qq = 0.f;
  #pragma unroll
  for (int i = 0; i < 6; i++){ float d = v[i]-mu; qq += d*d; }
  qq = wsum(qq);
  float rs = rsqrtf(qq * (1.f/384.f) + 1e-5f);
  int off = (4096 - (4096 >> (2*l))) / 3;
  int id  = off + (h >> l) * (32 >> l) + (w >> l);
  float invc = 1.f / (float)(1 << (2*l));
  float* ur = uniq + ((size_t)b * M_ + id) * R_;
  #pragma unroll
  for (int i = 0; i < 6; i++){
    int r = lane + i*64;
    float ln = (v[i]-mu)*rs*lw[r] + lb[r];
    atomicAdd(&ur[r], ln * invc);
  }
}

// ---------------- fp32 -> bf16 convert ----------------
__global__ void k_cvt(const float* __restrict__ src, unsigned short* __restrict__ dst, int n){
  int i = blockIdx.x * 256 + threadIdx.x;
  if (i < n) dst[i] = f2b(src[i]);
}

// ---------------- transpose + convert: src K x N fp32 -> dst N x K bf16 ----------------
__global__ void k_tcvt(const float* __restrict__ src, unsigned short* __restrict__ dst,
                       int K, int N){
  __shared__ float t[32][33];
  int n0 = blockIdx.x * 32, k0 = blockIdx.y * 32;
  int tx = threadIdx.x, ty = threadIdx.y;
  #pragma unroll
  for (int i = 0; i < 4; i++)
    t[ty + i*8][tx] = src[(size_t)(k0 + ty + i*8) * N + n0 + tx];
  __syncthreads();
  #pragma unroll
  for (int i = 0; i < 4; i++)
    dst[(size_t)(n0 + ty + i*8) * K + k0 + tx] = f2b(t[tx][ty + i*8]);
}

// ---------------- bf16 MFMA GEMM (128x128 tile, 2-phase) ----------------
// Kept for the small GEMMs (QKV EPI=5, attn-out EPI=0) where M/N aren't %256.
template<int EPI>
__global__ __launch_bounds__(256) void k_gemm(
    const unsigned short* __restrict__ A,   // M x K bf16
    const unsigned short* __restrict__ Bt,  // N x K bf16
    const float* __restrict__ bias,         // N
    void* __restrict__ Cout,
    const float* __restrict__ res,
    void* __restrict__ aux1, void* __restrict__ aux2,
    int Mtot, int N, int K){
  __shared__ unsigned short As[128*64];
  __shared__ unsigned short Bs[128*64];
  int m0 = blockIdx.x * 128, n0 = blockIdx.y * 128;
  int tid  = threadIdx.x;
  int wv   = tid >> 6, lane = tid & 63;
  int quad = lane >> 4, l16 = lane & 15;
  int wm = (wv >> 1) * 64, wn = (wv & 1) * 64;
  int lr = lane >> 3;          // row within 8-row chunk
  int lc = (lane & 7) * 8;     // short col within 64-col row
  f32x4 acc[4][4];
  #pragma unroll
  for (int a = 0; a < 4; a++)
    #pragma unroll
    for (int bidx = 0; bidx < 4; bidx++) acc[a][bidx] = 0.f;

  for (int k0 = 0; k0 < K; k0 += 64){
    #pragma unroll
    for (int j = 0; j < 4; j++){
      int c = wv*4 + j;            // chunk 0..15, 8 rows each
      int rowa = c*8 + lr;
      int gm = m0 + rowa; if (gm >= Mtot) gm = Mtot - 1;
      gload16(A + (size_t)gm * K + k0 + lc, &As[c*512]);
      int gn = n0 + rowa;          // N multiple of 128
      gload16(Bt + (size_t)gn * K + k0 + lc, &Bs[c*512]);
    }
    asm volatile("s_waitcnt vmcnt(0)" ::: "memory");
    __syncthreads();
    #pragma unroll
    for (int ko = 0; ko < 2; ko++){
      bf16x8 af[4], bfr[4];
      #pragma unroll
      for (int t = 0; t < 4; t++){
        af[t]  = *(const bf16x8*)(&As[(wm + t*16 + l16)*64 + ko*32 + quad*8]);
        bfr[t] = *(const bf16x8*)(&Bs[(wn + t*16 + l16)*64 + ko*32 + quad*8]);
      }
      #pragma unroll
      for (int mt = 0; mt < 4; mt++)
        #pragma unroll
        for (int nt = 0; nt < 4; nt++)
          acc[mt][nt] = __builtin_amdgcn_mfma_f32_16x16x32_bf16(
              af[mt], bfr[nt], acc[mt][nt], 0, 0, 0);
    }
    __syncthreads();
  }
  #pragma unroll
  for (int mt = 0; mt < 4; mt++){
    #pragma unroll
    for (int i = 0; i < 4; i++){
      int row = m0 + wm + mt*16 + quad*4 + i;
      if (row >= Mtot) continue;
      #pragma unroll
      for (int nt = 0; nt < 4; nt++){
        int col = n0 + wn + nt*16 + l16;
        size_t idx = (size_t)row * N + col;
        float vv = acc[mt][nt][i] + bias[col];
        if (EPI == 5){
          int bb = row / M_;
          int mm = row - bb * M_;
          if (col < 384){
            ((unsigned short*)Cout)[(size_t)row * R_ + col] = f2b(vv);
          } else if (col < 768){
            ((unsigned short*)aux1)[(size_t)row * R_ + col - 384] = f2b(vv);
          } else {
            int c2 = col - 768;
            int hh = c2 >> 6, dd = c2 & 63;
            ((unsigned short*)aux2)[(((size_t)(bb*NH_ + hh))*DH_ + dd)*MPAD_ + mm] = f2b(vv);
          }
        } else {
          ((float*)Cout)[idx] = vv;
        }
      }
    }
  }
}

// ================= 256x256 8-phase counted-vmcnt bf16 GEMM =================
// T2 (granule XOR swizzle, both-sides w/ global_load_lds) + T3/T4 (4 phases
// per K-tile, vmcnt(4) once per tile, never drained in steady state) +
// T5 (setprio around MFMA clusters). 8 waves (2M x 4N), per-wave C = 128x64.
// LDS: 2 buffers x (A 256x64 + B 256x64) bf16 = 128 KiB. 1 block/CU.
// REQUIRES: Mtot%256==0, N%256==0, kLen%64==0. K-range = [z*kLen, (z+1)*kLen).
// EPI 1: bias+gelu -> bf16.  EPI 3: fp32 atomicAdd into pre-initialized Cout.

__device__ __forceinline__ void stage_half(const unsigned short* __restrict__ g,
                                           unsigned short* l, int K){
  // stages 128 rows x 64 shorts; LDS dest linear [128][64]; global source
  // granule pre-swizzled (granule ^= row&7) so swizzled ds_read sees A[row][k].
  int tid = threadIdx.x;
  int w  = tid >> 6;                  // wave 0..7 -> rows w*16..w*16+15
  int ln = tid & 63;
  int rw = ln >> 3;                   // row within 8-row chunk (== row&7)
  int cs = ((ln & 7) ^ rw) * 8;       // swizzled short-col
  gload16(g + (size_t)(w*16 + rw)     * K + cs, l + (w*16)*64);
  gload16(g + (size_t)(w*16 + 8 + rw) * K + cs, l + (w*16 + 8)*64);
}

__device__ __forceinline__ bf16x8 ldsfrag(const unsigned short* base, int row, int ko, int quad){
  int g = ((ko << 2) + quad) ^ (row & 7);   // un-swizzle: slot g holds granule g^(row&7)
  return *(const bf16x8*)(base + row*64 + g*8);
}

#define PH_BAR()   asm volatile("s_barrier" ::: "memory")
#define PH_LGKM0() asm volatile("s_waitcnt lgkmcnt(0)" ::: "memory")

#define APHASE(MTBASE)                                                                 \
  {                                                                                    \
    bf16x8 af0l = ldsfrag(curA, wr*128 + (MTBASE)*16   + l16, 0, quad);                \
    bf16x8 af0h = ldsfrag(curA, wr*128 + (MTBASE)*16   + l16, 1, quad);                \
    bf16x8 af1l = ldsfrag(curA, wr*128 + (MTBASE+1)*16 + l16, 0, quad);                \
    bf16x8 af1h = ldsfrag(curA, wr*128 + (MTBASE+1)*16 + l16, 1, quad);                \
    PH_BAR(); PH_LGKM0();                                                              \
    __builtin_amdgcn_s_setprio(1);                                                     \
    _Pragma("unroll")                                                                  \
    for (int nt = 0; nt < 4; nt++){                                                    \
      acc[MTBASE][nt]   = __builtin_amdgcn_mfma_f32_16x16x32_bf16(af0l, bfr[nt][0], acc[MTBASE][nt],   0,0,0); \
      acc[MTBASE][nt]   = __builtin_amdgcn_mfma_f32_16x16x32_bf16(af0h, bfr[nt][1], acc[MTBASE][nt],   0,0,0); \
      acc[MTBASE+1][nt] = __builtin_amdgcn_mfma_f32_16x16x32_bf16(af1l, bfr[nt][0], acc[MTBASE+1][nt], 0,0,0); \
      acc[MTBASE+1][nt] = __builtin_amdgcn_mfma_f32_16x16x32_bf16(af1h, bfr[nt][1], acc[MTBASE+1][nt], 0,0,0); \
    }                                                                                  \
    __builtin_amdgcn_s_setprio(0);                                                     \
  }

template<int EPI>
__global__ __launch_bounds__(512, 2) void k_gemm8(
    const unsigned short* __restrict__ A,   // Mtot x Kfull bf16
    const unsigned short* __restrict__ Bt,  // N x Kfull bf16
    const float* __restrict__ bias,
    void* __restrict__ Cout,
    int Mtot, int N, int Kfull, int kLen){
  __shared__ unsigned short lds8[2][32768];  // [buf][A 256x64 | B 256x64]

  int m0 = blockIdx.x * 256, n0 = blockIdx.y * 256;
  int k0 = blockIdx.z * kLen;
  int NT = kLen >> 6;
  const size_t KS = (size_t)Kfull;
  const us* Ab = A  + (size_t)m0 * KS + k0;
  const us* Bb = Bt + (size_t)n0 * KS + k0;
  int tid = threadIdx.x, wv = tid >> 6, lane = tid & 63;
  int quad = lane >> 4, l16 = lane & 15;
  int wr = wv >> 2, wc = wv & 3;       // 2M x 4N wave grid

  f32x4 acc[8][4];
  #pragma unroll
  for (int a = 0; a < 8; a++)
    #pragma unroll
    for (int b = 0; b < 4; b++) acc[a][b] = 0.f;

  // ---- prologue: tile0 all 4 halves; tile1 B-halves (issue-order = steady state) ----
  stage_half(Bb,               &lds8[0][16384],        Kfull);  // H(0, B0)
  stage_half(Bb + 128*KS,      &lds8[0][16384 + 8192], Kfull);  // H(0, B1)
  stage_half(Ab,               &lds8[0][0],            Kfull);  // H(0, A0)
  stage_half(Ab + 128*KS,      &lds8[0][8192],         Kfull);  // H(0, A1)
  if (NT > 1){
    stage_half(Bb + 64,             &lds8[1][16384],        Kfull);  // H(1, B0)
    stage_half(Bb + 128*KS + 64,    &lds8[1][16384 + 8192], Kfull);  // H(1, B1)
    asm volatile("s_waitcnt vmcnt(4)" ::: "memory");
  } else {
    asm volatile("s_waitcnt vmcnt(0)" ::: "memory");
  }
  PH_BAR();

  for (int t = 0; t < NT; ++t){
    us* curA = &lds8[t & 1][0];
    us* curB = curA + 16384;
    us* nxtA = &lds8[(t + 1) & 1][0];
    bool st1 = (t + 1 < NT), st2 = (t + 2 < NT);
    const us* An = Ab + (size_t)(t + 1) * 64;
    const us* Bn = Bb + (size_t)(t + 2) * 64;
    bf16x8 bfr[4][2];

    // ---- phase 0: stage A0(t+1); read all B + A m0-1; MFMA m0-1 ----
    if (st1) stage_half(An, nxtA, Kfull);
    #pragma unroll
    for (int nt = 0; nt < 4; nt++){
      bfr[nt][0] = ldsfrag(curB, wc*64 + nt*16 + l16, 0, quad);
      bfr[nt][1] = ldsfrag(curB, wc*64 + nt*16 + l16, 1, quad);
    }
    APHASE(0);
    PH_BAR();

    // ---- phase 1: stage A1(t+1); MFMA m2-3 ----
    if (st1) stage_half(An + 128*KS, nxtA + 8192, Kfull);
    APHASE(2);
    PH_BAR();

    // ---- phase 2: stage B0(t+2) over dead B0(t); MFMA m4-5 ----
    if (st2) stage_half(Bn, curB, Kfull);
    APHASE(4);
    PH_BAR();

    // ---- phase 3: stage B1(t+2); MFMA m6-7; counted vmcnt; barrier ----
    if (st2) stage_half(Bn + 128*KS, curB + 8192, Kfull);
    APHASE(6);
    if (st1){
      if (st2) asm volatile("s_waitcnt vmcnt(4)" ::: "memory");
      else     asm volatile("s_waitcnt vmcnt(0)" ::: "memory");
    }
    PH_BAR();
  }

  // ---- epilogue ----
  #pragma unroll
  for (int mt = 0; mt < 8; mt++){
    #pragma unroll
    for (int i = 0; i < 4; i++){
      int row = m0 + wr*128 + mt*16 + quad*4 + i;
      #pragma unroll
      for (int nt = 0; nt < 4; nt++){
        int col = n0 + wc*64 + nt*16 + l16;
        size_t idx = (size_t)row * N + col;
        float vv = acc[mt][nt][i];
        if (EPI == 1){
          ((unsigned short*)Cout)[idx] = f2b(gelu_tanh(vv + bias[col]));
        } else {
          atomicAdd(&((float*)Cout)[idx], vv);
        }
      }
    }
  }
}

// ---------------- bf16 MFMA flash attention over M=1365 nodes ----------------
__global__ __launch_bounds__(256) void k_attn(
    const unsigned short* __restrict__ qb, const unsigned short* __restrict__ kb,
    const unsigned short* __restrict__ vtb, unsigned short* __restrict__ ob){
  __shared__ unsigned short Ks[64][64];
  __shared__ unsigned short Vt[64][64];
  __shared__ unsigned short Ps[4][16][64];
  int qt = blockIdx.x, bh = blockIdx.y;
  int b = bh / NH_, h = bh % NH_;
  int tid = threadIdx.x, wv = tid >> 6, lane = tid & 63;
  int quad = lane >> 4, l16 = lane & 15;

  int qm = qt*64 + wv*16 + l16;
  const unsigned short* qrow = qb + (size_t)(b*M_ + qm)*R_ + h*DH_;
  bf16x8 aq0 = *(const bf16x8*)(qrow + quad*8);
  bf16x8 aq1 = *(const bf16x8*)(qrow + 32 + quad*8);

  f32x4 oacc[4];
  #pragma unroll
  for (int db = 0; db < 4; db++) oacc[db] = 0.f;
  float mi[4], li[4];
  #pragma unroll
  for (int i = 0; i < 4; i++){ mi[i] = -1e30f; li[i] = 0.f; }

  for (int kt = 0; kt < 22; kt++){
    #pragma unroll
    for (int i = 0; i < 2; i++){
      int c = tid + i*256;
      int rowa = c >> 3, colc = (c & 7) * 8;
      *(uint4*)(&Ks[rowa][colc]) =
        *(const uint4*)(kb + (size_t)(b*M_ + kt*64 + rowa)*R_ + h*DH_ + colc);
      *(uint4*)(&Vt[rowa][colc]) =
        *(const uint4*)(vtb + ((size_t)bh*DH_ + rowa)*MPAD_ + kt*64 + colc);
    }
    __syncthreads();

    f32x4 s[4];
    #pragma unroll
    for (int nb = 0; nb < 4; nb++){
      s[nb] = 0.f;
      bf16x8 bk0 = *(const bf16x8*)(&Ks[nb*16 + l16][quad*8]);
      bf16x8 bk1 = *(const bf16x8*)(&Ks[nb*16 + l16][32 + quad*8]);
      s[nb] = __builtin_amdgcn_mfma_f32_16x16x32_bf16(aq0, bk0, s[nb], 0, 0, 0);
      s[nb] = __builtin_amdgcn_mfma_f32_16x16x32_bf16(aq1, bk1, s[nb], 0, 0, 0);
    }

    #pragma unroll
    for (int i = 0; i < 4; i++){
      float val[4];
      float mx = -1e30f;
      #pragma unroll
      for (int nb = 0; nb < 4; nb++){
        int gc = kt*64 + nb*16 + l16;
        val[nb] = (gc < M_) ? s[nb][i] * 0.125f : -1e30f;
        mx = fmaxf(mx, val[nb]);
      }
      mx = rmax16(mx);
      float mnew = fmaxf(mi[i], mx);
      float alpha = __expf(mi[i] - mnew);
      float rs = 0.f;
      #pragma unroll
      for (int nb = 0; nb < 4; nb++){
        float p = __expf(val[nb] - mnew);
        rs += p;
        Ps[wv][quad*4 + i][nb*16 + l16] = f2b(p);
      }
      rs = rsum16(rs);
      li[i] = li[i]*alpha + rs;
      mi[i] = mnew;
      #pragma unroll
      for (int db = 0; db < 4; db++) oacc[db][i] *= alpha;
    }

    #pragma unroll
    for (int ko = 0; ko < 2; ko++){
      bf16x8 ap = *(const bf16x8*)(&Ps[wv][l16][ko*32 + quad*8]);
      #pragma unroll
      for (int db = 0; db < 4; db++){
        bf16x8 bv = *(const bf16x8*)(&Vt[db*16 + l16][ko*32 + quad*8]);
        oacc[db] = __builtin_amdgcn_mfma_f32_16x16x32_bf16(ap, bv, oacc[db], 0, 0, 0);
      }
    }
    __syncthreads();
  }

  #pragma unroll
  for (int i = 0; i < 4; i++){
    int gm = qt*64 + wv*16 + quad*4 + i;
    if (gm < M_){
      float il = 1.f / li[i];
      #pragma unroll
      for (int db = 0; db < 4; db++)
        ob[(size_t)(b*M_ + gm)*R_ + h*DH_ + db*16 + l16] = f2b(oacc[db][i] * il);
    }
  }
}

// ---- scatter attn_out + residual -> xres; out = xres + b2 (MLP2 base); LN2 -> flat bf16 ----
__global__ __launch_bounds__(256) void k_scatter_ln2(
    const float* __restrict__ x, const float* __restrict__ attn,
    const float* __restrict__ lw, const float* __restrict__ lb,
    const float* __restrict__ b2,
    float* __restrict__ xres, unsigned short* __restrict__ flatb){
  int row  = blockIdx.x * 4 + (threadIdx.x >> 6);
  int lane = threadIdx.x & 63;
  int l  = row % 6;
  int hw = (row / 6) & 1023;
  int b  = row / 6144;
  int h = hw >> 5, w = hw & 31;
  int off = (4096 - (4096 >> (2*l))) / 3;
  int id  = off + (h >> l) * (32 >> l) + (w >> l);
  const float* ar = attn + ((size_t)b * M_ + id) * R_;
  const float* xr = x + (size_t)row * R_;
  float* orow = xres + (size_t)row * R_;
  float vv[6]; float s = 0.f;
  #pragma unroll
  for (int i = 0; i < 6; i++){
    int r = lane + i*64;
    float t = xr[r] + ar[r];
    vv[i] = t; s += t;
    orow[r] = t + b2[l*R_ + r];     // pre-fold bias: MLP2 partials atomicAdd onto this
  }
  s = wsum(s);
  float mu = s * (1.f/384.f);
  float qq = 0.f;
  #pragma unroll
  for (int i = 0; i < 6; i++){ float d = vv[i]-mu; qq += d*d; }
  qq = wsum(qq);
  float rs = rsqrtf(qq * (1.f/384.f) + 1e-5f);
  unsigned short* fr = flatb + (size_t)row * R_;
  #pragma unroll
  for (int i = 0; i < 6; i++){
    int r = lane + i*64;
    fr[r] = f2b((vv[i]-mu)*rs*lw[r] + lb[r]);
  }
}

extern "C" void kernel_launch(void* const* d_in, const int* in_sizes, int n_in,
                              void* d_out, int out_size, void* d_ws, size_t ws_size,
                              hipStream_t stream){
  const float* x    = (const float*)d_in[0];
  const float* ln1w = (const float*)d_in[1];
  const float* ln1b = (const float*)d_in[2];
  const float* ln2w = (const float*)d_in[3];
  const float* ln2b = (const float*)d_in[4];
  const float* wq   = (const float*)d_in[5];
  const float* bq   = (const float*)d_in[6];
  const float* wk   = (const float*)d_in[7];
  const float* bk   = (const float*)d_in[8];
  const float* wvv  = (const float*)d_in[9];
  const float* bv   = (const float*)d_in[10];
  const float* wo   = (const float*)d_in[11];
  const float* bo   = (const float*)d_in[12];
  const float* w1   = (const float*)d_in[13];
  const float* b1   = (const float*)d_in[14];
  const float* w2   = (const float*)d_in[15];
  const float* b2   = (const float*)d_in[16];
  float* out = (float*)d_out;

  // ---- workspace layout ----
  char* ws = (char*)d_ws;
  unsigned short* h1b = (unsigned short*)ws;                     // 8192*9216 bf16 (reuses region A)
  unsigned short* qb  = (unsigned short*)ws;
  unsigned short* kb  = qb + (size_t)BMR_ * R_;
  unsigned short* vtb = kb + (size_t)BMR_ * R_;
  unsigned short* ob  = vtb + (size_t)B_ * NH_ * DH_ * MPAD_;
  float* attn_o = (float*)(ob + (size_t)BMR_ * R_);
  size_t regA = ((size_t)8192 * HID_ * 2 + 255) & ~(size_t)255;
  char* p = ws + regA;
  float* uniqf = (float*)p;                   p += (size_t)BMR_ * R_ * 4;
  unsigned short* uniqb = (unsigned short*)p; p += (size_t)BMR_ * R_ * 2;
  unsigned short* wqkvt = (unsigned short*)p; p += (size_t)3 * R_ * R_ * 2;
  unsigned short* wot = (unsigned short*)p;   p += (size_t)R_ * R_ * 2;
  unsigned short* w1t = (unsigned short*)p;   p += (size_t)NE_ * HID_ * 2;
  unsigned short* w2t = (unsigned short*)p;   p += (size_t)NE_ * HID_ * 2;
  unsigned short* flatb = (unsigned short*)p; p += (size_t)NROW_ * R_ * 2;
  float* bqkv = (float*)p;                    p += (size_t)3 * R_ * 4;

  hipMemsetAsync(uniqf, 0, (size_t)BMR_ * R_ * 4, stream);
  hipMemsetAsync(vtb, 0, (size_t)B_ * NH_ * DH_ * MPAD_ * 2, stream);
  hipMemcpyAsync(bqkv,        bq, R_*4, hipMemcpyDeviceToDevice, stream);
  hipMemcpyAsync(bqkv + R_,   bk, R_*4, hipMemcpyDeviceToDevice, stream);
  hipMemcpyAsync(bqkv + 2*R_, bv, R_*4, hipMemcpyDeviceToDevice, stream);

  k_ln1_scatter<<<NROW_/4, 256, 0, stream>>>(x, ln1w, ln1b, uniqf);
  k_cvt<<<(BMR_*R_ + 255)/256, 256, 0, stream>>>(uniqf, uniqb, BMR_*R_);

  dim3 tb(32, 8);
  k_tcvt<<<dim3(R_/32, R_/32), tb, 0, stream>>>(wq, wqkvt, R_, R_);
  k_tcvt<<<dim3(R_/32, R_/32), tb, 0, stream>>>(wk, wqkvt + (size_t)R_*R_, R_, R_);
  k_tcvt<<<dim3(R_/32, R_/32), tb, 0, stream>>>(wvv, wqkvt + (size_t)2*R_*R_, R_, R_);
  k_tcvt<<<dim3(R_/32, R_/32), tb, 0, stream>>>(wo, wot, R_, R_);
  k_tcvt<<<dim3(HID_/32, NE_/32), tb, 0, stream>>>(w1, w1t, NE_, HID_);
  k_tcvt<<<dim3(NE_/32, HID_/32), tb, 0, stream>>>(w2, w2t, HID_, NE_);

  // merged QKV: N = 1152
  k_gemm<5><<<dim3(86, 9), 256, 0, stream>>>(uniqb, wqkvt, bqkv, qb, nullptr,
                                             kb, vtb, BMR_, 3*R_, R_);

  k_attn<<<dim3(22, 48), 256, 0, stream>>>(qb, kb, vtb, ob);

  k_gemm<0><<<dim3(86, 3), 256, 0, stream>>>(ob, wot, bo, attn_o, nullptr,
                                             nullptr, nullptr, BMR_, R_, R_);

  k_scatter_ln2<<<NROW_/4, 256, 0, stream>>>(x, attn_o, ln2w, ln2b, b2, out, flatb);

  // MLP up-proj: 8192x9216 = flatb(8192x2304) @ w1t^T, gelu -> bf16
  k_gemm8<1><<<dim3(32, 36), 512, 0, stream>>>(flatb, w1t, b1, h1b,
                                               8192, HID_, NE_, NE_);
  // MLP down-proj: split-K=2, fp32 atomicAdd onto out (= xres + b2)
  k_gemm8<3><<<dim3(32, 9, 2), 512, 0, stream>>>(h1b, w2t, nullptr, out,
                                                 8192, NE_, HID_, HID_/2);
}

// Round 2
// 1414.804 us; speedup vs baseline: 1.4273x; 1.0622x over previous
//
#include <hip/hip_runtime.h>
#include <cstddef>

#define B_    8
#define H_    32
#define W_    32
#define L_    6
#define R_    384
#define NH_   6
#define DH_   64
#define M_    1365
#define MPAD_ 1408
#define NE_   2304
#define HID_  9216
#define NROW_ 49152   // B*H*W*L
#define BMR_  10920   // B*M

typedef __bf16 bf16x8 __attribute__((ext_vector_type(8)));
typedef float  f32x4  __attribute__((ext_vector_type(4)));
typedef unsigned short us;

__device__ __forceinline__ unsigned short f2b(float f){
  unsigned u = __float_as_uint(f);
  u = (u + 0x7FFFu + ((u >> 16) & 1u)) >> 16;
  return (unsigned short)u;
}

__device__ __forceinline__ void gload16(const unsigned short* g, unsigned short* l){
  __builtin_amdgcn_global_load_lds(
      (const __attribute__((address_space(1))) unsigned int*)g,
      (__attribute__((address_space(3))) unsigned int*)l,
      16, 0, 0);
}

__device__ __forceinline__ float wsum(float s){
  #pragma unroll
  for (int o = 32; o > 0; o >>= 1) s += __shfl_xor(s, o, 64);
  return s;
}

__device__ __forceinline__ float rmax16(float v){
  v = fmaxf(v, __shfl_xor(v, 1, 64));
  v = fmaxf(v, __shfl_xor(v, 2, 64));
  v = fmaxf(v, __shfl_xor(v, 4, 64));
  v = fmaxf(v, __shfl_xor(v, 8, 64));
  return v;
}
__device__ __forceinline__ float rsum16(float v){
  v += __shfl_xor(v, 1, 64);
  v += __shfl_xor(v, 2, 64);
  v += __shfl_xor(v, 4, 64);
  v += __shfl_xor(v, 8, 64);
  return v;
}

// gelu(tanh approx) == x * sigmoid(1.5957691216*(x + 0.044715*x^3)) exactly.
__device__ __forceinline__ float gelu_fast(float x){
  float t = fmaf(0.07135482f * x, x * x, 1.5957691216f * x);
  return x / (1.0f + __expf(-t));
}

// ---------------- LN1 + scaled atomic scatter into uniq (B,M,R) ----------------
__global__ __launch_bounds__(256) void k_ln1_scatter(
    const float* __restrict__ x, const float* __restrict__ lw,
    const float* __restrict__ lb, float* __restrict__ uniq){
  int row  = blockIdx.x * 4 + (threadIdx.x >> 6);
  int lane = threadIdx.x & 63;
  int l  = row % 6;
  int hw = (row / 6) & 1023;
  int b  = row / 6144;
  int h = hw >> 5, w = hw & 31;
  const float* xr = x + (size_t)row * R_;
  float v[6]; float s = 0.f;
  #pragma unroll
  for (int i = 0; i < 6; i++){ v[i] = xr[lane + i*64]; s += v[i]; }
  s = wsum(s);
  float mu = s * (1.f/384.f);
  float qq = 0.f;
  #pragma unroll
  for (int i = 0; i < 6; i++){ float d = v[i]-mu; qq += d*d; }
  qq = wsum(qq);
  float rs = rsqrtf(qq * (1.f/384.f) + 1e-5f);
  int off = (4096 - (4096 >> (2*l))) / 3;
  int id  = off + (h >> l) * (32 >> l) + (w >> l);
  float invc = 1.f / (float)(1 << (2*l));
  float* ur = uniq + ((size_t)b * M_ + id) * R_;
  #pragma unroll
  for (int i = 0; i < 6; i++){
    int r = lane + i*64;
    float ln = (v[i]-mu)*rs*lw[r] + lb[r];
    atomicAdd(&ur[r], ln * invc);
  }
}

// ---------------- fp32 -> bf16 convert ----------------
__global__ void k_cvt(const float* __restrict__ src, unsigned short* __restrict__ dst, int n){
  int i = blockIdx.x * 256 + threadIdx.x;
  if (i < n) dst[i] = f2b(src[i]);
}

// ---------------- transpose + convert: src K x N fp32 -> dst N x K bf16 ----------------
__global__ void k_tcvt(const float* __restrict__ src, unsigned short* __restrict__ dst,
                       int K, int N){
  __shared__ float t[32][33];
  int n0 = blockIdx.x * 32, k0 = blockIdx.y * 32;
  int tx = threadIdx.x, ty = threadIdx.y;
  #pragma unroll
  for (int i = 0; i < 4; i++)
    t[ty + i*8][tx] = src[(size_t)(k0 + ty + i*8) * N + n0 + tx];
  __syncthreads();
  #pragma unroll
  for (int i = 0; i < 4; i++)
    dst[(size_t)(n0 + ty + i*8) * K + k0 + tx] = f2b(t[tx][ty + i*8]);
}

// ---------------- bf16 MFMA GEMM (128x128 tile, 2-phase) ----------------
// Kept for the small GEMMs (QKV EPI=5, attn-out EPI=0) where M/N aren't %256.
template<int EPI>
__global__ __launch_bounds__(256) void k_gemm(
    const unsigned short* __restrict__ A,   // M x K bf16
    const unsigned short* __restrict__ Bt,  // N x K bf16
    const float* __restrict__ bias,         // N
    void* __restrict__ Cout,
    const float* __restrict__ res,
    void* __restrict__ aux1, void* __restrict__ aux2,
    int Mtot, int N, int K){
  __shared__ unsigned short As[128*64];
  __shared__ unsigned short Bs[128*64];
  int m0 = blockIdx.x * 128, n0 = blockIdx.y * 128;
  int tid  = threadIdx.x;
  int wv   = tid >> 6, lane = tid & 63;
  int quad = lane >> 4, l16 = lane & 15;
  int wm = (wv >> 1) * 64, wn = (wv & 1) * 64;
  int lr = lane >> 3;          // row within 8-row chunk
  int lc = (lane & 7) * 8;     // short col within 64-col row
  f32x4 acc[4][4];
  #pragma unroll
  for (int a = 0; a < 4; a++)
    #pragma unroll
    for (int bidx = 0; bidx < 4; bidx++) acc[a][bidx] = 0.f;

  for (int k0 = 0; k0 < K; k0 += 64){
    #pragma unroll
    for (int j = 0; j < 4; j++){
      int c = wv*4 + j;            // chunk 0..15, 8 rows each
      int rowa = c*8 + lr;
      int gm = m0 + rowa; if (gm >= Mtot) gm = Mtot - 1;
      gload16(A + (size_t)gm * K + k0 + lc, &As[c*512]);
      int gn = n0 + rowa;          // N multiple of 128
      gload16(Bt + (size_t)gn * K + k0 + lc, &Bs[c*512]);
    }
    asm volatile("s_waitcnt vmcnt(0)" ::: "memory");
    __syncthreads();
    #pragma unroll
    for (int ko = 0; ko < 2; ko++){
      bf16x8 af[4], bfr[4];
      #pragma unroll
      for (int t = 0; t < 4; t++){
        af[t]  = *(const bf16x8*)(&As[(wm + t*16 + l16)*64 + ko*32 + quad*8]);
        bfr[t] = *(const bf16x8*)(&Bs[(wn + t*16 + l16)*64 + ko*32 + quad*8]);
      }
      #pragma unroll
      for (int mt = 0; mt < 4; mt++)
        #pragma unroll
        for (int nt = 0; nt < 4; nt++)
          acc[mt][nt] = __builtin_amdgcn_mfma_f32_16x16x32_bf16(
              af[mt], bfr[nt], acc[mt][nt], 0, 0, 0);
    }
    __syncthreads();
  }
  #pragma unroll
  for (int mt = 0; mt < 4; mt++){
    #pragma unroll
    for (int i = 0; i < 4; i++){
      int row = m0 + wm + mt*16 + quad*4 + i;
      if (row >= Mtot) continue;
      #pragma unroll
      for (int nt = 0; nt < 4; nt++){
        int col = n0 + wn + nt*16 + l16;
        size_t idx = (size_t)row * N + col;
        float vv = acc[mt][nt][i] + bias[col];
        if (EPI == 5){
          int bb = row / M_;
          int mm = row - bb * M_;
          if (col < 384){
            ((unsigned short*)Cout)[(size_t)row * R_ + col] = f2b(vv);
          } else if (col < 768){
            ((unsigned short*)aux1)[(size_t)row * R_ + col - 384] = f2b(vv);
          } else {
            int c2 = col - 768;
            int hh = c2 >> 6, dd = c2 & 63;
            ((unsigned short*)aux2)[(((size_t)(bb*NH_ + hh))*DH_ + dd)*MPAD_ + mm] = f2b(vv);
          }
        } else {
          ((float*)Cout)[idx] = vv;
        }
      }
    }
  }
}

// ================= 256x256 bulk-issue counted-vmcnt bf16 GEMM =================
// Evolution of the 8-phase template: all frag ds_reads for a K-tile are issued
// up-front (compiler emits counted lgkmcnt waits), MFMA clusters run while the
// LDS queue drains -> LDS pipe overlaps MFMA pipe. Only TWO s_barriers per
// K-tile: mid-tile (guards in-place restage of B(t+2) over dead B(t)) and
// end-of-tile. Counted vmcnt(4) keeps 2 half-tiles in flight, never drains to 0
// in steady state. T2 granule swizzle (both-sides) unchanged; T5 setprio kept.
// 8 waves (2M x 4N), per-wave C = 128x64. LDS 128 KiB -> 1 block/CU.
// REQUIRES: Mtot%256==0, N%256==0, kLen%64==0.
// EPI 1: bias+gelu -> bf16.  EPI 3: fp32 atomicAdd into pre-initialized Cout.

__device__ __forceinline__ void stage_half(const unsigned short* __restrict__ g,
                                           unsigned short* l, int K){
  // stages 128 rows x 64 shorts; LDS dest linear [128][64]; global source
  // granule pre-swizzled (granule ^= row&7) so swizzled ds_read sees A[row][k].
  int tid = threadIdx.x;
  int w  = tid >> 6;                  // wave 0..7 -> rows w*16..w*16+15
  int ln = tid & 63;
  int rw = ln >> 3;                   // row within 8-row chunk (== row&7)
  int cs = ((ln & 7) ^ rw) * 8;       // swizzled short-col
  gload16(g + (size_t)(w*16 + rw)     * K + cs, l + (w*16)*64);
  gload16(g + (size_t)(w*16 + 8 + rw) * K + cs, l + (w*16 + 8)*64);
}

__device__ __forceinline__ bf16x8 ldsfrag(const unsigned short* base, int row, int ko, int quad){
  int g = ((ko << 2) + quad) ^ (row & 7);   // un-swizzle: slot g holds granule g^(row&7)
  return *(const bf16x8*)(base + row*64 + g*8);
}

#define SB0()      __builtin_amdgcn_sched_barrier(0)
#define CLUSTER(I0, I1, F0, F1)                                                        \
  {                                                                                    \
    __builtin_amdgcn_s_setprio(1);                                                     \
    _Pragma("unroll")                                                                  \
    for (int nt = 0; nt < 4; nt++){                                                    \
      acc[I0][nt] = __builtin_amdgcn_mfma_f32_16x16x32_bf16(F0[0], bfr[nt][0], acc[I0][nt], 0,0,0); \
      acc[I0][nt] = __builtin_amdgcn_mfma_f32_16x16x32_bf16(F0[1], bfr[nt][1], acc[I0][nt], 0,0,0); \
      acc[I1][nt] = __builtin_amdgcn_mfma_f32_16x16x32_bf16(F1[0], bfr[nt][0], acc[I1][nt], 0,0,0); \
      acc[I1][nt] = __builtin_amdgcn_mfma_f32_16x16x32_bf16(F1[1], bfr[nt][1], acc[I1][nt], 0,0,0); \
    }                                                                                  \
    __builtin_amdgcn_s_setprio(0);                                                     \
  }

template<int EPI>
__global__ __launch_bounds__(512, 2) void k_gemm8(
    const unsigned short* __restrict__ A,   // Mtot x Kfull bf16
    const unsigned short* __restrict__ Bt,  // N x Kfull bf16
    const float* __restrict__ bias,
    void* __restrict__ Cout,
    int Mtot, int N, int Kfull, int kLen){
  __shared__ unsigned short lds8[2][32768];  // [buf][A 256x64 | B 256x64]

  int m0 = blockIdx.x * 256, n0 = blockIdx.y * 256;
  int k0 = blockIdx.z * kLen;
  int NT = kLen >> 6;
  const size_t KS = (size_t)Kfull;
  const us* Ab = A  + (size_t)m0 * KS + k0;
  const us* Bb = Bt + (size_t)n0 * KS + k0;
  int tid = threadIdx.x, wv = tid >> 6, lane = tid & 63;
  int quad = lane >> 4, l16 = lane & 15;
  int wr = wv >> 2, wc = wv & 3;       // 2M x 4N wave grid

  f32x4 acc[8][4];
  #pragma unroll
  for (int a = 0; a < 8; a++)
    #pragma unroll
    for (int b = 0; b < 4; b++) acc[a][b] = 0.f;

  // ---- prologue: tile0 all 4 halves into buf0; tile1 B-halves into buf1 ----
  stage_half(Bb,               &lds8[0][16384],        Kfull);  // H(0, B0)
  stage_half(Bb + 128*KS,      &lds8[0][16384 + 8192], Kfull);  // H(0, B1)
  stage_half(Ab,               &lds8[0][0],            Kfull);  // H(0, A0)
  stage_half(Ab + 128*KS,      &lds8[0][8192],         Kfull);  // H(0, A1)
  if (NT > 1){
    stage_half(Bb + 64,             &lds8[1][16384],        Kfull);  // H(1, B0)
    stage_half(Bb + 128*KS + 64,    &lds8[1][16384 + 8192], Kfull);  // H(1, B1)
    asm volatile("s_waitcnt vmcnt(4)" ::: "memory");
  } else {
    asm volatile("s_waitcnt vmcnt(0)" ::: "memory");
  }
  asm volatile("s_barrier" ::: "memory");
  SB0();

  for (int t = 0; t < NT; ++t){
    us* curA = &lds8[t & 1][0];
    us* curB = curA + 16384;
    us* nxtA = &lds8[(t + 1) & 1][0];
    bool st1 = (t + 1 < NT), st2 = (t + 2 < NT);
    const us* An = Ab + (size_t)(t + 1) * 64;
    const us* Bn = Bb + (size_t)(t + 2) * 64;

    // ---- issue all B frags + A rows m0..m3 (16 ds_read_b128) ----
    bf16x8 bfr[4][2], aA[4][2], aB[2][2], aC[2][2];
    #pragma unroll
    for (int nt = 0; nt < 4; nt++){
      bfr[nt][0] = ldsfrag(curB, wc*64 + nt*16 + l16, 0, quad);
      bfr[nt][1] = ldsfrag(curB, wc*64 + nt*16 + l16, 1, quad);
    }
    #pragma unroll
    for (int mt = 0; mt < 4; mt++){
      aA[mt][0] = ldsfrag(curA, wr*128 + mt*16 + l16, 0, quad);
      aA[mt][1] = ldsfrag(curA, wr*128 + mt*16 + l16, 1, quad);
    }
    // ---- prefetch A(t+1) into other buffer (HBM latency hides under MFMA) ----
    if (st1){
      stage_half(An,          nxtA,        Kfull);
      stage_half(An + 128*KS, nxtA + 8192, Kfull);
    }

    // ---- cluster 0 (rows m0,m1) while remaining ds_reads drain ----
    CLUSTER(0, 1, aA[0], aA[1]);
    #pragma unroll
    for (int mt = 0; mt < 2; mt++){
      aB[mt][0] = ldsfrag(curA, wr*128 + (4+mt)*16 + l16, 0, quad);
      aB[mt][1] = ldsfrag(curA, wr*128 + (4+mt)*16 + l16, 1, quad);
    }
    // ---- cluster 1 (rows m2,m3) ----
    CLUSTER(2, 3, aA[2], aA[3]);

    // ---- mid barrier: all waves consumed B frags -> B(t+2) restage safe ----
    SB0();
    __builtin_amdgcn_s_barrier();
    SB0();
    if (st2){
      stage_half(Bn,          curB,        Kfull);
      stage_half(Bn + 128*KS, curB + 8192, Kfull);
    }
    #pragma unroll
    for (int mt = 0; mt < 2; mt++){
      aC[mt][0] = ldsfrag(curA, wr*128 + (6+mt)*16 + l16, 0, quad);
      aC[mt][1] = ldsfrag(curA, wr*128 + (6+mt)*16 + l16, 1, quad);
    }
    // ---- clusters 2,3 (rows m4..m7) ----
    CLUSTER(4, 5, aB[0], aB[1]);
    CLUSTER(6, 7, aC[0], aC[1]);

    // ---- counted vmcnt: drain A(t+1)+B(t+1), keep B(t+2) in flight ----
    if (st1){
      if (st2) asm volatile("s_waitcnt vmcnt(4)" ::: "memory");
      else     asm volatile("s_waitcnt vmcnt(0)" ::: "memory");
    }
    SB0();
    __builtin_amdgcn_s_barrier();
    SB0();
  }

  // ---- epilogue ----
  #pragma unroll
  for (int mt = 0; mt < 8; mt++){
    #pragma unroll
    for (int i = 0; i < 4; i++){
      int row = m0 + wr*128 + mt*16 + quad*4 + i;
      #pragma unroll
      for (int nt = 0; nt < 4; nt++){
        int col = n0 + wc*64 + nt*16 + l16;
        size_t idx = (size_t)row * N + col;
        float vv = acc[mt][nt][i];
        if (EPI == 1){
          ((unsigned short*)Cout)[idx] = f2b(gelu_fast(vv + bias[col]));
        } else {
          atomicAdd(&((float*)Cout)[idx], vv);
        }
      }
    }
  }
}

// ---------------- bf16 MFMA flash attention over M=1365 nodes ----------------
__global__ __launch_bounds__(256) void k_attn(
    const unsigned short* __restrict__ qb, const unsigned short* __restrict__ kb,
    const unsigned short* __restrict__ vtb, unsigned short* __restrict__ ob){
  __shared__ unsigned short Ks[64][64];
  __shared__ unsigned short Vt[64][64];
  __shared__ unsigned short Ps[4][16][64];
  int qt = blockIdx.x, bh = blockIdx.y;
  int b = bh / NH_, h = bh % NH_;
  int tid = threadIdx.x, wv = tid >> 6, lane = tid & 63;
  int quad = lane >> 4, l16 = lane & 15;

  int qm = qt*64 + wv*16 + l16;
  const unsigned short* qrow = qb + (size_t)(b*M_ + qm)*R_ + h*DH_;
  bf16x8 aq0 = *(const bf16x8*)(qrow + quad*8);
  bf16x8 aq1 = *(const bf16x8*)(qrow + 32 + quad*8);

  f32x4 oacc[4];
  #pragma unroll
  for (int db = 0; db < 4; db++) oacc[db] = 0.f;
  float mi[4], li[4];
  #pragma unroll
  for (int i = 0; i < 4; i++){ mi[i] = -1e30f; li[i] = 0.f; }

  for (int kt = 0; kt < 22; kt++){
    #pragma unroll
    for (int i = 0; i < 2; i++){
      int c = tid + i*256;
      int rowa = c >> 3, colc = (c & 7) * 8;
      *(uint4*)(&Ks[rowa][colc]) =
        *(const uint4*)(kb + (size_t)(b*M_ + kt*64 + rowa)*R_ + h*DH_ + colc);
      *(uint4*)(&Vt[rowa][colc]) =
        *(const uint4*)(vtb + ((size_t)bh*DH_ + rowa)*MPAD_ + kt*64 + colc);
    }
    __syncthreads();

    f32x4 s[4];
    #pragma unroll
    for (int nb = 0; nb < 4; nb++){
      s[nb] = 0.f;
      bf16x8 bk0 = *(const bf16x8*)(&Ks[nb*16 + l16][quad*8]);
      bf16x8 bk1 = *(const bf16x8*)(&Ks[nb*16 + l16][32 + quad*8]);
      s[nb] = __builtin_amdgcn_mfma_f32_16x16x32_bf16(aq0, bk0, s[nb], 0, 0, 0);
      s[nb] = __builtin_amdgcn_mfma_f32_16x16x32_bf16(aq1, bk1, s[nb], 0, 0, 0);
    }

    #pragma unroll
    for (int i = 0; i < 4; i++){
      float val[4];
      float mx = -1e30f;
      #pragma unroll
      for (int nb = 0; nb < 4; nb++){
        int gc = kt*64 + nb*16 + l16;
        val[nb] = (gc < M_) ? s[nb][i] * 0.125f : -1e30f;
        mx = fmaxf(mx, val[nb]);
      }
      mx = rmax16(mx);
      float mnew = fmaxf(mi[i], mx);
      float alpha = __expf(mi[i] - mnew);
      float rs = 0.f;
      #pragma unroll
      for (int nb = 0; nb < 4; nb++){
        float p = __expf(val[nb] - mnew);
        rs += p;
        Ps[wv][quad*4 + i][nb*16 + l16] = f2b(p);
      }
      rs = rsum16(rs);
      li[i] = li[i]*alpha + rs;
      mi[i] = mnew;
      #pragma unroll
      for (int db = 0; db < 4; db++) oacc[db][i] *= alpha;
    }

    #pragma unroll
    for (int ko = 0; ko < 2; ko++){
      bf16x8 ap = *(const bf16x8*)(&Ps[wv][l16][ko*32 + quad*8]);
      #pragma unroll
      for (int db = 0; db < 4; db++){
        bf16x8 bv = *(const bf16x8*)(&Vt[db*16 + l16][ko*32 + quad*8]);
        oacc[db] = __builtin_amdgcn_mfma_f32_16x16x32_bf16(ap, bv, oacc[db], 0, 0, 0);
      }
    }
    __syncthreads();
  }

  #pragma unroll
  for (int i = 0; i < 4; i++){
    int gm = qt*64 + wv*16 + quad*4 + i;
    if (gm < M_){
      float il = 1.f / li[i];
      #pragma unroll
      for (int db = 0; db < 4; db++)
        ob[(size_t)(b*M_ + gm)*R_ + h*DH_ + db*16 + l16] = f2b(oacc[db][i] * il);
    }
  }
}

// ---- scatter attn_out + residual -> xres; out = xres + b2 (MLP2 base); LN2 -> flat bf16 ----
__global__ __launch_bounds__(256) void k_scatter_ln2(
    const float* __restrict__ x, const float* __restrict__ attn,
    const float* __restrict__ lw, const float* __restrict__ lb,
    const float* __restrict__ b2,
    float* __restrict__ xres, unsigned short* __restrict__ flatb){
  int row  = blockIdx.x * 4 + (threadIdx.x >> 6);
  int lane = threadIdx.x & 63;
  int l  = row % 6;
  int hw = (row / 6) & 1023;
  int b  = row / 6144;
  int h = hw >> 5, w = hw & 31;
  int off = (4096 - (4096 >> (2*l))) / 3;
  int id  = off + (h >> l) * (32 >> l) + (w >> l);
  const float* ar = attn + ((size_t)b * M_ + id) * R_;
  const float* xr = x + (size_t)row * R_;
  float* orow = xres + (size_t)row * R_;
  float vv[6]; float s = 0.f;
  #pragma unroll
  for (int i = 0; i < 6; i++){
    int r = lane + i*64;
    float t = xr[r] + ar[r];
    vv[i] = t; s += t;
    orow[r] = t + b2[l*R_ + r];     // pre-fold bias: MLP2 partials atomicAdd onto this
  }
  s = wsum(s);
  float mu = s * (1.f/384.f);
  float qq = 0.f;
  #pragma unroll
  for (int i = 0; i < 6; i++){ float d = vv[i]-mu; qq += d*d; }
  qq = wsum(qq);
  float rs = rsqrtf(qq * (1.f/384.f) + 1e-5f);
  unsigned short* fr = flatb + (size_t)row * R_;
  #pragma unroll
  for (int i = 0; i < 6; i++){
    int r = lane + i*64;
    fr[r] = f2b((vv[i]-mu)*rs*lw[r] + lb[r]);
  }
}

extern "C" void kernel_launch(void* const* d_in, const int* in_sizes, int n_in,
                              void* d_out, int out_size, void* d_ws, size_t ws_size,
                              hipStream_t stream){
  const float* x    = (const float*)d_in[0];
  const float* ln1w = (const float*)d_in[1];
  const float* ln1b = (const float*)d_in[2];
  const float* ln2w = (const float*)d_in[3];
  const float* ln2b = (const float*)d_in[4];
  const float* wq   = (const float*)d_in[5];
  const float* bq   = (const float*)d_in[6];
  const float* wk   = (const float*)d_in[7];
  const float* bk   = (const float*)d_in[8];
  const float* wvv  = (const float*)d_in[9];
  const float* bv   = (const float*)d_in[10];
  const float* wo   = (const float*)d_in[11];
  const float* bo   = (const float*)d_in[12];
  const float* w1   = (const float*)d_in[13];
  const float* b1   = (const float*)d_in[14];
  const float* w2   = (const float*)d_in[15];
  const float* b2   = (const float*)d_in[16];
  float* out = (float*)d_out;

  // ---- workspace layout ----
  char* ws = (char*)d_ws;
  unsigned short* h1b = (unsigned short*)ws;                     // 8192*9216 bf16 (reuses region A)
  unsigned short* qb  = (unsigned short*)ws;
  unsigned short* kb  = qb + (size_t)BMR_ * R_;
  unsigned short* vtb = kb + (size_t)BMR_ * R_;
  unsigned short* ob  = vtb + (size_t)B_ * NH_ * DH_ * MPAD_;
  float* attn_o = (float*)(ob + (size_t)BMR_ * R_);
  size_t regA = ((size_t)8192 * HID_ * 2 + 255) & ~(size_t)255;
  char* p = ws + regA;
  float* uniqf = (float*)p;                   p += (size_t)BMR_ * R_ * 4;
  unsigned short* uniqb = (unsigned short*)p; p += (size_t)BMR_ * R_ * 2;
  unsigned short* wqkvt = (unsigned short*)p; p += (size_t)3 * R_ * R_ * 2;
  unsigned short* wot = (unsigned short*)p;   p += (size_t)R_ * R_ * 2;
  unsigned short* w1t = (unsigned short*)p;   p += (size_t)NE_ * HID_ * 2;
  unsigned short* w2t = (unsigned short*)p;   p += (size_t)NE_ * HID_ * 2;
  unsigned short* flatb = (unsigned short*)p; p += (size_t)NROW_ * R_ * 2;
  float* bqkv = (float*)p;                    p += (size_t)3 * R_ * 4;

  hipMemsetAsync(uniqf, 0, (size_t)BMR_ * R_ * 4, stream);
  hipMemsetAsync(vtb, 0, (size_t)B_ * NH_ * DH_ * MPAD_ * 2, stream);
  hipMemcpyAsync(bqkv,        bq, R_*4, hipMemcpyDeviceToDevice, stream);
  hipMemcpyAsync(bqkv + R_,   bk, R_*4, hipMemcpyDeviceToDevice, stream);
  hipMemcpyAsync(bqkv + 2*R_, bv, R_*4, hipMemcpyDeviceToDevice, stream);

  k_ln1_scatter<<<NROW_/4, 256, 0, stream>>>(x, ln1w, ln1b, uniqf);
  k_cvt<<<(BMR_*R_ + 255)/256, 256, 0, stream>>>(uniqf, uniqb, BMR_*R_);

  dim3 tb(32, 8);
  k_tcvt<<<dim3(R_/32, R_/32), tb, 0, stream>>>(wq, wqkvt, R_, R_);
  k_tcvt<<<dim3(R_/32, R_/32), tb, 0, stream>>>(wk, wqkvt + (size_t)R_*R_, R_, R_);
  k_tcvt<<<dim3(R_/32, R_/32), tb, 0, stream>>>(wvv, wqkvt + (size_t)2*R_*R_, R_, R_);
  k_tcvt<<<dim3(R_/32, R_/32), tb, 0, stream>>>(wo, wot, R_, R_);
  k_tcvt<<<dim3(HID_/32, NE_/32), tb, 0, stream>>>(w1, w1t, NE_, HID_);
  k_tcvt<<<dim3(NE_/32, HID_/32), tb, 0, stream>>>(w2, w2t, HID_, NE_);

  // merged QKV: N = 1152
  k_gemm<5><<<dim3(86, 9), 256, 0, stream>>>(uniqb, wqkvt, bqkv, qb, nullptr,
                                             kb, vtb, BMR_, 3*R_, R_);

  k_attn<<<dim3(22, 48), 256, 0, stream>>>(qb, kb, vtb, ob);

  k_gemm<0><<<dim3(86, 3), 256, 0, stream>>>(ob, wot, bo, attn_o, nullptr,
                                             nullptr, nullptr, BMR_, R_, R_);

  k_scatter_ln2<<<NROW_/4, 256, 0, stream>>>(x, attn_o, ln2w, ln2b, b2, out, flatb);

  // MLP up-proj: 8192x9216 = flatb(8192x2304) @ w1t^T, gelu -> bf16
  k_gemm8<1><<<dim3(32, 36), 512, 0, stream>>>(flatb, w1t, b1, h1b,
                                               8192, HID_, NE_, NE_);
  // MLP down-proj: split-K=2, fp32 atomicAdd onto out (= xres + b2)
  k_gemm8<3><<<dim3(32, 9, 2), 512, 0, stream>>>(h1b, w2t, nullptr, out,
                                                 8192, NE_, HID_, HID_/2);
}